// Round 7
// baseline (191.087 us; speedup 1.0000x reference)
//
#include <hip/hip_runtime.h>
#include <math.h>

#define BB 2
#define NN 2048
#define MM 4096
#define DD 256
#define HH 8
#define DK 32
#define KNN 16

typedef __attribute__((ext_vector_type(8))) short short8;
typedef __attribute__((ext_vector_type(4))) short short4v;
typedef __attribute__((ext_vector_type(4))) float f32x4;
typedef unsigned long long u64;
typedef unsigned short u16;

static __device__ __forceinline__ u16 f2bf(float f) {
    union { float f; unsigned u; } v; v.f = f;
    unsigned r = v.u + 0x7FFF + ((v.u >> 16) & 1);   // round-to-nearest-even
    return (u16)(r >> 16);
}
static __device__ __forceinline__ float bf2f(u16 u) {
    union { unsigned u; float f; } v; v.u = ((unsigned)u) << 16;
    return v.f;
}

// =================== wtrans: transpose + cvt the five 256x256 weights ===================
__global__ __launch_bounds__(256)
void wtrans(const float* W0, const float* W1, const float* W2, const float* W3, const float* W4,
            u16* O0, u16* O1, u16* O2, u16* O3, u16* O4)
{
    __shared__ float tile[64][65];
    const int bid = blockIdx.x;               // 5 * 16 blocks
    const int m = bid >> 4, tl = bid & 15;
    const int tr = (tl >> 2) * 64, tc = (tl & 3) * 64;
    const float* W = m == 0 ? W0 : m == 1 ? W1 : m == 2 ? W2 : m == 3 ? W3 : W4;
    u16*        O = m == 0 ? O0 : m == 1 ? O1 : m == 2 ? O2 : m == 3 ? O3 : O4;
    const int c = threadIdx.x & 63, r4 = threadIdx.x >> 6;
    #pragma unroll
    for (int i = 0; i < 16; ++i) {
        const int r = (r4 << 4) + i;
        tile[r][c] = W[(size_t)(tr + r) * 256 + tc + c];
    }
    __syncthreads();
    #pragma unroll
    for (int i = 0; i < 16; ++i) {
        const int cc = (r4 << 4) + i;
        O[(size_t)(tc + cc) * 256 + tr + c] = f2bf(tile[c][cc]);
    }
}

// 64x64-tile bf16 MFMA GEMM body; A staged from f32 with inline cvt.
static __device__ __forceinline__ void gemm64_body(
    const float* __restrict__ A, size_t row0, const u16* __restrict__ WT, int col0,
    u16* As, u16* Bs, int t, f32x4 acc[2][2])
{
    const int lane = t & 63, w = t >> 6;
    const int wr = (w >> 1) * 32, wc = (w & 1) * 32;
    for (int k0 = 0; k0 < 256; k0 += 64) {
        #pragma unroll
        for (int e = 0; e < 2; ++e) {
            const int flat = t + (e << 8);
            const int r = flat >> 3, kc = (flat & 7) << 3;
            const int off = ((r << 7) + (kc << 1)) ^ ((r & 7) << 4);
            const float* ap = A + (row0 + r) * 256 + k0 + kc;
            float4 a0 = *(const float4*)ap;
            float4 a1 = *(const float4*)(ap + 4);
            short8 s;
            s[0] = (short)f2bf(a0.x); s[1] = (short)f2bf(a0.y);
            s[2] = (short)f2bf(a0.z); s[3] = (short)f2bf(a0.w);
            s[4] = (short)f2bf(a1.x); s[5] = (short)f2bf(a1.y);
            s[6] = (short)f2bf(a1.z); s[7] = (short)f2bf(a1.w);
            *(short8*)((char*)As + off) = s;
            *(short8*)((char*)Bs + off) = *(const short8*)(WT + (size_t)(col0 + r) * 256 + k0 + kc);
        }
        __syncthreads();
        #pragma unroll
        for (int kk = 0; kk < 64; kk += 32) {
            const int kbo = (kk + ((lane >> 4) << 3)) << 1;
            short8 af[2], bfr[2];
            #pragma unroll
            for (int i = 0; i < 2; ++i) {
                const int ra = wr + (i << 4) + (lane & 15);
                af[i]  = *(const short8*)((const char*)As + (((ra << 7) + kbo) ^ ((ra & 7) << 4)));
                const int rb = wc + (i << 4) + (lane & 15);
                bfr[i] = *(const short8*)((const char*)Bs + (((rb << 7) + kbo) ^ ((rb & 7) << 4)));
            }
            #pragma unroll
            for (int mi = 0; mi < 2; ++mi)
                #pragma unroll
                for (int ni = 0; ni < 2; ++ni)
                    acc[mi][ni] = __builtin_amdgcn_mfma_f32_16x16x32_bf16(af[mi], bfr[ni], acc[mi][ni], 0, 0, 0);
        }
        __syncthreads();
    }
}

// cold path: exhausted lane rescans its 64 candidates for min key > last
static __device__ __forceinline__ unsigned refill_min(
    const float* __restrict__ tb, int lane, float px, float py, float pz,
    float x2, unsigned last)
{
    unsigned best = 0xFFFFFFFFu;
    #pragma unroll 1
    for (int j = 0; j < 64; ++j) {
        const int m = (j << 6) + lane;
        const float tx = tb[m*3+0], ty = tb[m*3+1], tz = tb[m*3+2];
        const float y2 = tx*tx + ty*ty + tz*tz;
        float d = (x2 + y2) - 2.0f*(px*tx + py*ty + pz*tz);
        d = d > 0.f ? d : 0.f;
        const unsigned k = ((unsigned)fminf(d*32768.f, 1048574.f) << 12) | (unsigned)m;
        if (k > last && k < best) best = k;
    }
    return best;
}

// =================== mega: knn + KV-GEMM + Q-GEMM + zero(avg), role-interleaved ===================
// 2304 blocks = 256 groups x 9 roles: 0-1 knn | 2-5 KV | 6 Q | 7-8 zero
__global__ __launch_bounds__(256, 4)
void mega_kernel(const float* __restrict__ src, const float* __restrict__ tgt,
                 int* __restrict__ knn_idx,
                 const float* __restrict__ tgt_fea, const float* __restrict__ src_fea,
                 const u16* __restrict__ WTq, const u16* __restrict__ WTkv,
                 const float* __restrict__ bq, const float* __restrict__ bk,
                 const float* __restrict__ bv,
                 float* __restrict__ Qb, u16* __restrict__ Kbf, u16* __restrict__ Vbf,
                 float* __restrict__ avg)
{
    __shared__ u16 As[64 * 64];   // 8KB
    __shared__ u16 Bs[64 * 64];   // 8KB
    const int bid = blockIdx.x;
    const int t = threadIdx.x;
    const int lane = t & 63;
    const int lid = bid / 9;
    const int role = bid % 9;

    if (role < 2) {
        // ---- kNN v4: 2 queries/wave; per-lane sorted top-4 cache + 20 pop-rounds
        const int kb = lid * 2 + role;                 // 0..511
        const int wid = t >> 6;
        const int bn0 = (kb << 3) + (wid << 1);        // queries bn0, bn0+1
        const int b = bn0 >> 11;
        const float* spA = src + (size_t)bn0 * 3;
        const float pxA = spA[0], pyA = spA[1], pzA = spA[2];
        const float pxB = spA[3], pyB = spA[4], pzB = spA[5];
        const float x2A = pxA*pxA + pyA*pyA + pzA*pzA;
        const float x2B = pxB*pxB + pyB*pyB + pzB*pzB;
        const float* tb = tgt + (size_t)b * MM * 3;
        unsigned sA0=~0u,sA1=~0u,sA2=~0u,sA3=~0u;
        unsigned sB0=~0u,sB1=~0u,sB2=~0u,sB3=~0u;
        #pragma unroll 8
        for (int j = 0; j < 64; ++j) {
            const int m = (j << 6) + lane;
            const float tx = tb[m*3+0], ty = tb[m*3+1], tz = tb[m*3+2];
            const float y2 = tx*tx + ty*ty + tz*tz;
            float dA = (x2A + y2) - 2.0f*(pxA*tx + pyA*ty + pzA*tz);
            float dB = (x2B + y2) - 2.0f*(pxB*tx + pyB*ty + pzB*tz);
            dA = dA > 0.f ? dA : 0.f;
            dB = dB > 0.f ? dB : 0.f;
            const unsigned kA = ((unsigned)fminf(dA*32768.f, 1048574.f) << 12) | (unsigned)m;
            const unsigned kB = ((unsigned)fminf(dB*32768.f, 1048574.f) << 12) | (unsigned)m;
            if (kA < sA3) {
                sA3 = kA; unsigned tt;
                tt=sA2; sA2=tt<sA3?tt:sA3; sA3=tt<sA3?sA3:tt;
                tt=sA1; sA1=tt<sA2?tt:sA2; sA2=tt<sA2?sA2:tt;
                tt=sA0; sA0=tt<sA1?tt:sA1; sA1=tt<sA1?sA1:tt;
            }
            if (kB < sB3) {
                sB3 = kB; unsigned tt;
                tt=sB2; sB2=tt<sB3?tt:sB3; sB3=tt<sB3?sB3:tt;
                tt=sB1; sB1=tt<sB2?tt:sB2; sB2=tt<sB2?sB2:tt;
                tt=sB0; sB0=tt<sB1?tt:sB1; sB1=tt<sB1?sB1:tt;
            }
        }
        unsigned lastA = 0, lastB = 0, myA = 0, myB = 0;
        for (int sel = 0; sel < 20; ++sel) {
            if (__any(sA0 == 0xFFFFFFFFu)) {           // rare refill
                if (sA0 == 0xFFFFFFFFu) sA0 = refill_min(tb, lane, pxA,pyA,pzA, x2A, lastA);
            }
            if (__any(sB0 == 0xFFFFFFFFu)) {
                if (sB0 == 0xFFFFFFFFu) sB0 = refill_min(tb, lane, pxB,pyB,pzB, x2B, lastB);
            }
            unsigned wA = sA0, wB = sB0;
            #pragma unroll
            for (int s2 = 1; s2 <= 32; s2 <<= 1) {
                const unsigned oA = __shfl_xor(wA, s2, 64); wA = oA < wA ? oA : wA;
                const unsigned oB = __shfl_xor(wB, s2, 64); wB = oB < wB ? oB : wB;
            }
            if (lane == sel) { myA = wA; myB = wB; }
            if (sA0 == wA) { lastA = sA0; sA0=sA1; sA1=sA2; sA2=sA3; sA3=0xFFFFFFFFu; }
            if (sB0 == wB) { lastB = sB0; sB0=sB1; sB1=sB2; sB2=sB3; sB3=0xFFFFFFFFu; }
        }
        // exact f64 re-rank of the two top-20 supersets (np tie-break by index)
        const int midxA = (int)(myA & 0xFFFu);
        const int midxB = (int)(myB & 0xFFFu);
        u64 exA = ~0ULL, exB = ~0ULL;
        if (lane < 20) {
            {
                const float* tp = tb + (size_t)midxA * 3;
                const double pxd = pxA, pyd = pyA, pzd = pzA;
                const double tx = tp[0], ty = tp[1], tz = tp[2];
                const double x2d = pxd*pxd + pyd*pyd + pzd*pzd;
                const double y2d = tx*tx + ty*ty + tz*tz;
                double dd = (x2d + y2d) - 2.0*(pxd*tx + pyd*ty + pzd*tz);
                dd = dd > 0.0 ? dd : 0.0;
                exA = (((u64)__double_as_longlong(dd)) & ~0xFFFULL) | (u64)midxA;
            }
            {
                const float* tp = tb + (size_t)midxB * 3;
                const double pxd = pxB, pyd = pyB, pzd = pzB;
                const double tx = tp[0], ty = tp[1], tz = tp[2];
                const double x2d = pxd*pxd + pyd*pyd + pzd*pzd;
                const double y2d = tx*tx + ty*ty + tz*tz;
                double dd = (x2d + y2d) - 2.0*(pxd*tx + pyd*ty + pzd*tz);
                dd = dd > 0.0 ? dd : 0.0;
                exB = (((u64)__double_as_longlong(dd)) & ~0xFFFULL) | (u64)midxB;
            }
        }
        int rankA = 0, rankB = 0;
        #pragma unroll
        for (int i = 0; i < 20; ++i) {
            rankA += (__shfl(exA, i, 64) < exA) ? 1 : 0;
            rankB += (__shfl(exB, i, 64) < exB) ? 1 : 0;
        }
        if (lane < 20 && rankA < 16) knn_idx[(size_t)bn0 * KNN + rankA] = midxA;
        if (lane < 20 && rankB < 16) knn_idx[((size_t)bn0 + 1) * KNN + rankB] = midxB;
        return;
    }

    if (role < 6) {
        // ---- KV GEMM: [8192][512] = tgt_fea @ [WTk|WTv]^T, bf16 out, 64x64 tile
        const int kvb = lid * 4 + (role - 2);          // 0..1023
        const size_t row0 = (size_t)(kvb >> 3) * 64;
        const int col0 = (kvb & 7) * 64;
        f32x4 acc[2][2] = {};
        gemm64_body(tgt_fea, row0, WTkv, col0, As, Bs, t, acc);
        const int w = t >> 6;
        const int wr = (w >> 1) * 32, wc = (w & 1) * 32;
        const bool isv = col0 >= 256;
        u16* ob = isv ? Vbf : Kbf;
        const float* bs = isv ? bv : bk;
        const int cb = (isv ? col0 - 256 : col0) + wc;
        const int cq = lane & 15, rq = (lane >> 4) << 2;
        #pragma unroll
        for (int ni = 0; ni < 2; ++ni) {
            const int c = cb + (ni << 4) + cq;
            const float bval = bs[c];
            #pragma unroll
            for (int mi = 0; mi < 2; ++mi) {
                const size_t r = row0 + wr + (mi << 4) + rq;
                #pragma unroll
                for (int e = 0; e < 4; ++e)
                    ob[(r + e) * 256 + c] = f2bf(acc[mi][ni][e] + bval);
            }
        }
        return;
    }

    if (role == 6) {
        // ---- Q GEMM: [4096][256] f32 = src_fea @ WTq^T, 64x64 tile
        const int qb = lid;                            // 0..255
        const size_t row0 = (size_t)(qb >> 2) * 64;
        const int col0 = (qb & 3) * 64;
        f32x4 acc[2][2] = {};
        gemm64_body(src_fea, row0, WTq, col0, As, Bs, t, acc);
        const int w = t >> 6;
        const int wr = (w >> 1) * 32, wc = (w & 1) * 32;
        const int cq = lane & 15, rq = (lane >> 4) << 2;
        #pragma unroll
        for (int ni = 0; ni < 2; ++ni) {
            const int c = col0 + wc + (ni << 4) + cq;
            const float bval = bq[c];
            #pragma unroll
            for (int mi = 0; mi < 2; ++mi) {
                const size_t rbase = (row0 + wr + (mi << 4) + rq) * 256 + c;
                #pragma unroll
                for (int e = 0; e < 4; ++e)
                    Qb[rbase + (size_t)e * 256] = acc[mi][ni][e] + bval;
            }
        }
        return;
    }

    // ---- zero avg_attn: 16.78M f32 via f32x4
    {
        const int zb = lid * 2 + (role - 7);           // 0..511
        f32x4 z = {0.f, 0.f, 0.f, 0.f};
        f32x4* pz = (f32x4*)avg;
        const int base = zb * 256 + t;
        #pragma unroll
        for (int i = 0; i < 32; ++i)
            pz[base + i * 131072] = z;
    }
}

// =================== tail: attn + Wo1+LN+ReLU + Wo2, fused. 256 blocks x 1024 thr ===================
// Block owns 16 rows. 16 waves: attn = 1 query/wave; GEMMs: wave = 16-col strip, M=16.
__global__ __launch_bounds__(1024)
void tail_kernel(const float* __restrict__ Q, const u16* __restrict__ Kb,
                 const u16* __restrict__ Vb, const int* __restrict__ knn_idx,
                 const float* __restrict__ src_fea,
                 const u16* __restrict__ WTo1, const float* __restrict__ bo1,
                 const float* __restrict__ lng, const float* __restrict__ lnb,
                 const u16* __restrict__ WTo2, const float* __restrict__ bo2,
                 float* __restrict__ updated, float* __restrict__ avg_attn)
{
    __shared__ float q_sh[16][256];        // 16KB
    __shared__ float pw_sh[16][8][17];     // 8.5KB
    __shared__ int   idx_sh[16][16];       // 1KB
    __shared__ u16   Xs[16 * 256];         // 8KB, XOR-swizzled rows
    __shared__ u16   Hs[16 * 256];         // 8KB, XOR-swizzled rows
    __shared__ float2 red2[16][16];        // [wave][row] partial (s1,s2), 2KB
    const int t = threadIdx.x;
    const int wid = t >> 6, lane = t & 63;
    const int r0 = blockIdx.x << 4;
    const int bn = r0 + wid;
    const int b = bn >> 11;
    const int h = lane >> 3, k2 = lane & 7;

    // ---- attn: one query per wave ----
    *(float4*)&q_sh[wid][lane << 2] = *(const float4*)(Q + (size_t)bn * 256 + (lane << 2));
    const int ia = knn_idx[(size_t)bn * KNN + k2];
    const int ib = knn_idx[(size_t)bn * KNN + 8 + k2];
    __syncthreads();

    const u16* Ka = Kb + ((size_t)b * MM + ia) * 256 + h * DK;
    const u16* Kc = Kb + ((size_t)b * MM + ib) * 256 + h * DK;
    const float* qh = &q_sh[wid][h * DK];
    float s0 = 0.f, s1 = 0.f;
    #pragma unroll
    for (int j = 0; j < DK; j += 8) {
        const short8 ka = *(const short8*)(Ka + j);
        const short8 kc = *(const short8*)(Kc + j);
        #pragma unroll
        for (int e = 0; e < 8; ++e) {
            const float qv = qh[j + e];
            s0 = fmaf(qv, bf2f((u16)ka[e]), s0);
            s1 = fmaf(qv, bf2f((u16)kc[e]), s1);
        }
    }
    s0 *= 0.17677669529663688f;
    s1 *= 0.17677669529663688f;

    float mx = fmaxf(s0, s1);
    mx = fmaxf(mx, __shfl_xor(mx, 1, 64));
    mx = fmaxf(mx, __shfl_xor(mx, 2, 64));
    mx = fmaxf(mx, __shfl_xor(mx, 4, 64));
    const float e0 = expf(s0 - mx), e1 = expf(s1 - mx);
    float sum = e0 + e1;
    sum += __shfl_xor(sum, 1, 64);
    sum += __shfl_xor(sum, 2, 64);
    sum += __shfl_xor(sum, 4, 64);
    const float inv = 1.0f / sum;
    const float p0 = e0 * inv, p1 = e1 * inv;

    float a0 = p0, a1 = p1;
    a0 += __shfl_xor(a0, 8, 64);  a1 += __shfl_xor(a1, 8, 64);
    a0 += __shfl_xor(a0, 16, 64); a1 += __shfl_xor(a1, 16, 64);
    a0 += __shfl_xor(a0, 32, 64); a1 += __shfl_xor(a1, 32, 64);
    if (h == 0) {
        avg_attn[(size_t)bn * MM + ia] = a0 * 0.125f;
        avg_attn[(size_t)bn * MM + ib] = a1 * 0.125f;
        idx_sh[wid][k2] = ia;
        idx_sh[wid][8 + k2] = ib;
    }
    pw_sh[wid][h][k2] = p0;
    pw_sh[wid][h][8 + k2] = p1;
    __syncthreads();

    {   // PV + residual -> Xs (bf16, swizzled)
        const int d0 = lane << 2;
        const int h2 = lane >> 3;
        float o0 = 0.f, o1 = 0.f, o2 = 0.f, o3 = 0.f;
        #pragma unroll
        for (int k = 0; k < KNN; ++k) {
            const float p = pw_sh[wid][h2][k];
            const int ik = idx_sh[wid][k];
            const short4v v4 = *(const short4v*)(Vb + ((size_t)b * MM + ik) * 256 + d0);
            o0 = fmaf(p, bf2f((u16)v4[0]), o0);
            o1 = fmaf(p, bf2f((u16)v4[1]), o1);
            o2 = fmaf(p, bf2f((u16)v4[2]), o2);
            o3 = fmaf(p, bf2f((u16)v4[3]), o3);
        }
        const float4 sf = *(const float4*)(src_fea + (size_t)bn * 256 + d0);
        short4v xo;
        xo[0] = (short)f2bf(o0 + sf.x);
        xo[1] = (short)f2bf(o1 + sf.y);
        xo[2] = (short)f2bf(o2 + sf.z);
        xo[3] = (short)f2bf(o3 + sf.w);
        const int off = ((wid << 9) + (d0 << 1)) ^ ((wid & 7) << 4);
        *(short4v*)((char*)Xs + off) = xo;
    }
    __syncthreads();

    // ---- Wo1 (M=16) + bias + LN + ReLU -> Hs ----
    const int cq = lane & 15, ks = lane >> 4;          // ks: 0..3
    const int colB = (wid << 4) + cq;                  // this wave's 16-col strip
    f32x4 acc = {};
    #pragma unroll
    for (int kk = 0; kk < 256; kk += 32) {
        const int k8 = kk + (ks << 3);
        const short8 af = *(const short8*)((const char*)Xs + (((cq << 9) + (k8 << 1)) ^ ((cq & 7) << 4)));
        const short8 bfrg = *(const short8*)(WTo1 + (size_t)colB * 256 + k8);
        acc = __builtin_amdgcn_mfma_f32_16x16x32_bf16(af, bfrg, acc, 0, 0, 0);
    }
    {
        const float bval = bo1[colB];
        #pragma unroll
        for (int e = 0; e < 4; ++e) acc[e] += bval;
    }
    {   // per-row partial sums over this wave's 16 cols (butterfly over lane bits 0-3)
        float s1v[4], s2v[4];
        #pragma unroll
        for (int e = 0; e < 4; ++e) {
            float v = acc[e], vv = acc[e] * acc[e];
            v += __shfl_xor(v, 1, 64); vv += __shfl_xor(vv, 1, 64);
            v += __shfl_xor(v, 2, 64); vv += __shfl_xor(vv, 2, 64);
            v += __shfl_xor(v, 4, 64); vv += __shfl_xor(vv, 4, 64);
            v += __shfl_xor(v, 8, 64); vv += __shfl_xor(vv, 8, 64);
            s1v[e] = v; s2v[e] = vv;
        }
        if (cq == 0) {
            #pragma unroll
            for (int e = 0; e < 4; ++e) {
                float2 pr; pr.x = s1v[e]; pr.y = s2v[e];
                red2[wid][(ks << 2) + e] = pr;
            }
        }
    }
    __syncthreads();
    {
        const float gv = lng[colB], bv = lnb[colB];
        #pragma unroll
        for (int e = 0; e < 4; ++e) {
            const int r = (ks << 2) + e;
            float S1 = 0.f, S2 = 0.f;
            #pragma unroll
            for (int w2 = 0; w2 < 16; ++w2) {
                const float2 pr = red2[w2][r];
                S1 += pr.x; S2 += pr.y;
            }
            const float mean = S1 * (1.0f / 256.0f);
            const float var = S2 * (1.0f / 256.0f) - mean * mean;
            const float rstd = 1.0f / sqrtf(var + 1e-5f);
            const float y = (acc[e] - mean) * rstd * gv + bv;
            const int off = ((r << 9) + (colB << 1)) ^ ((r & 7) << 4);
            *(u16*)((char*)Hs + off) = f2bf(fmaxf(y, 0.0f));
        }
    }
    __syncthreads();

    // ---- Wo2 (M=16) -> updated (f32) ----
    f32x4 acc2 = {};
    #pragma unroll
    for (int kk = 0; kk < 256; kk += 32) {
        const int k8 = kk + (ks << 3);
        const short8 af = *(const short8*)((const char*)Hs + (((cq << 9) + (k8 << 1)) ^ ((cq & 7) << 4)));
        const short8 bfrg = *(const short8*)(WTo2 + (size_t)colB * 256 + k8);
        acc2 = __builtin_amdgcn_mfma_f32_16x16x32_bf16(af, bfrg, acc2, 0, 0, 0);
    }
    {
        const float bval = bo2[colB];
        #pragma unroll
        for (int e = 0; e < 4; ++e) {
            const int r = (ks << 2) + e;
            updated[(size_t)(r0 + r) * 256 + colB] = acc2[e] + bval;
        }
    }
}

extern "C" void kernel_launch(void* const* d_in, const int* in_sizes, int n_in,
                              void* d_out, int out_size, void* d_ws, size_t ws_size,
                              hipStream_t stream) {
    const float* src     = (const float*)d_in[0];
    const float* tgt     = (const float*)d_in[1];
    const float* src_fea = (const float*)d_in[2];
    const float* tgt_fea = (const float*)d_in[3];
    const float* Wq  = (const float*)d_in[4];   const float* bq  = (const float*)d_in[5];
    const float* Wk  = (const float*)d_in[6];   const float* bk  = (const float*)d_in[7];
    const float* Wv  = (const float*)d_in[8];   const float* bv  = (const float*)d_in[9];
    const float* Wo1 = (const float*)d_in[10];  const float* bo1 = (const float*)d_in[11];
    const float* lng = (const float*)d_in[12];  const float* lnb = (const float*)d_in[13];
    const float* Wo2 = (const float*)d_in[14];  const float* bo2 = (const float*)d_in[15];
    (void)in_sizes; (void)n_in; (void)out_size; (void)ws_size;

    float* out     = (float*)d_out;
    float* updated = out;                                   // [B,N,D] f32
    float* avg     = out + (size_t)BB * NN * DD;            // [B,N,M] f32

    char* p = (char*)d_ws;
    u16* WTq  = (u16*)p;   p += 256 * 256 * 2;
    u16* WTk  = (u16*)p;   p += 256 * 256 * 2;              // WTk|WTv contiguous = WTkv
    u16* WTv  = (u16*)p;   p += 256 * 256 * 2;
    u16* WTo1 = (u16*)p;   p += 256 * 256 * 2;
    u16* WTo2 = (u16*)p;   p += 256 * 256 * 2;
    float* Qb = (float*)p; p += (size_t)BB * NN * DD * 4;   // 4MB
    u16* Kbf  = (u16*)p;   p += (size_t)BB * MM * DD * 2;   // 4MB
    u16* Vbf  = (u16*)p;   p += (size_t)BB * MM * DD * 2;   // 4MB
    int* knn  = (int*)p;   p += (size_t)BB * NN * KNN * 4;  // 256KB

    dim3 blk(256);
    wtrans<<<80, blk, 0, stream>>>(Wq, Wk, Wv, Wo1, Wo2, WTq, WTk, WTv, WTo1, WTo2);
    mega_kernel<<<2304, blk, 0, stream>>>(src, tgt, knn, tgt_fea, src_fea, WTq, WTk,
                                          bq, bk, bv, Qb, Kbf, Vbf, avg);
    tail_kernel<<<256, dim3(1024), 0, stream>>>(Qb, Kbf, Vbf, knn, src_fea,
                                                WTo1, bo1, lng, lnb, WTo2, bo2,
                                                updated, avg);
}